// Round 15
// baseline (261.456 us; speedup 1.0000x reference)
//
#include <hip/hip_runtime.h>

// VQ-VAE quantization: z [16384 x 512] f32, codebook [8192 x 512] f32.
// out = concat(z_st [16384*512] f32, vq_loss [1] f32).
//
// R4: MX-fp8 (e4m3, K=128 scaled MFMA) GEMM; packed (dist|idx) u32 argmin.
// R17 (249.3 best): atomicMin candidate reduce (candV array gone), pure
// streaming gather.
// R18 (this): occupancy over dbuf. The dbuf never paid (R14 counted-vmcnt
// null; R11/R12 null/regressed) because 2 blocks/CU gives no co-resident
// work to hide the per-block stage drain; R0's bf16 ran this exact
// single-buffer 2-barrier structure at 4 blocks/CU and hit a higher
// fraction of its MFMA rate. Single 16KB As + 16KB Bs -> 33KB LDS ->
// 4 blocks/CU (launch_bounds(256,4); 2nd arg = blocks/CU on this hipcc,
// R7-measured). Cross-block overlap hides stage latency (m114).
// Everything else identical to R17.

#define M_ROWS 16384
#define K_CODES 8192
#define DIM 512
#define BM 128
#define BN 128
#define BK 128                 // fp8 bytes per K-step (one 16x16x128 MFMA)
#define NT (K_CODES / BN)      // 64 ktiles
#define OUT0_SIZE (M_ROWS * DIM)
#define GB_BLOCKS 1024

typedef int   i32x8 __attribute__((ext_vector_type(8)));
typedef float f32x4 __attribute__((ext_vector_type(4)));

template <bool HI>
__device__ __forceinline__ int pk8(float a, float b, int old) {
    return __builtin_amdgcn_cvt_pk_fp8_f32(a, b, old, HI);
}

__device__ __forceinline__ void gload_lds(const unsigned char* g, unsigned char* l) {
    __builtin_amdgcn_global_load_lds((const __attribute__((address_space(1))) void*)g,
                                     (__attribute__((address_space(3))) void*)l, 16, 0, 0);
}

// ---- kernel 1: fused converts + candMin init ---------------------------
__global__ __launch_bounds__(256) void convert_all(
    const float* __restrict__ z, const float* __restrict__ cb,
    unsigned char* __restrict__ z8, unsigned char* __restrict__ cb8,
    float* __restrict__ enorm, unsigned int* __restrict__ candMin,
    float* __restrict__ lossSlot)
{
    const int tid = threadIdx.x;
    if (blockIdx.x == 0 && tid == 0) *lossSlot = 0.f;   // gather accumulates
    {   // blocks 0..63 init candMin[16384]
        int gi = blockIdx.x * 256 + tid;
        if (gi < M_ROWS) candMin[gi] = 0xFFFFFFFFu;
    }
    if (blockIdx.x < K_CODES / 4) {
        const int w = tid >> 6, lane = tid & 63;
        const int row = blockIdx.x * 4 + w;
        const float* src = cb + (size_t)row * DIM + lane * 8;
        float4 a = *(const float4*)(src);
        float4 b = *(const float4*)(src + 4);
        float ns = a.x * a.x + a.y * a.y + a.z * a.z + a.w * a.w
                 + b.x * b.x + b.y * b.y + b.z * b.z + b.w * b.w;
        const float S = 8192.0f;                 // exact power of 2
        int lo = 0, hi = 0;
        lo = pk8<false>(a.x * S, a.y * S, lo); lo = pk8<true>(a.z * S, a.w * S, lo);
        hi = pk8<false>(b.x * S, b.y * S, hi); hi = pk8<true>(b.z * S, b.w * S, hi);
        *(int2*)(cb8 + (size_t)row * DIM + lane * 8) = make_int2(lo, hi);
        for (int m = 32; m; m >>= 1) ns += __shfl_down(ns, m, 64);
        if (lane == 0) enorm[row] = S * ns;      // 8192 * ||e||^2 (f32-exact norm)
    } else {
        size_t i = ((size_t)(blockIdx.x - K_CODES / 4) * 256 + tid) * 8;
        float4 a = *(const float4*)(z + i);
        float4 b = *(const float4*)(z + i + 4);
        int lo = 0, hi = 0;
        lo = pk8<false>(a.x, a.y, lo); lo = pk8<true>(a.z, a.w, lo);
        hi = pk8<false>(b.x, b.y, hi); hi = pk8<true>(b.z, b.w, hi);
        *(int2*)(z8 + i) = make_int2(lo, hi);
    }
}

// ---- kernel 2: MX-fp8 GEMM (128x128, 4 waves, 4 blocks/CU) + atomicMin -
__global__ __launch_bounds__(256, 4) void gemm_argmin(
    const unsigned char* __restrict__ z8, const unsigned char* __restrict__ cbb,
    const float* __restrict__ enorm, unsigned int* __restrict__ candMin)
{
    __shared__ alignas(32) unsigned char As[BM * BK];   // 16 KB single buffer
    __shared__ alignas(32) unsigned char Bs[BN * BK];   // 16 KB single buffer
    __shared__ float Es[BN];

    const int tid = threadIdx.x;
    const int lane = tid & 63;
    const int w = tid >> 6;             // 0..3
    // XCD remap: b&7 = XCD; XCD owns mtiles [xcd*16,xcd*16+16) (1MB A
    // slice, L2-hot); ktile advances every 128 blocks.
    const int b = blockIdx.x;
    const int xcd = b & 7;
    const int idx = b >> 3;             // 0..1023
    const int ktile = idx >> 4;         // 0..63
    const int mtile = xcd * 16 + (idx & 15);
    const int mbase = mtile * BM;
    const int nbase = ktile * BN;

    if (tid < BN) Es[tid] = enorm[nbase + tid];

    f32x4 acc[16];
#pragma unroll
    for (int i = 0; i < 16; ++i) acc[i] = (f32x4){0.f, 0.f, 0.f, 0.f};

    const int rA = lane >> 3;           // row within 8-row chunk
    const int jG = ((lane & 7) ^ rA) * 16;  // pre-swizzled global 16B chunk
    const int quad = lane >> 4;
    const int l15 = lane & 15;
    const int sw = l15 & 7;
    const int rw = (w >> 1) * 64;       // wave row quadrant
    const int cw = (w & 1) * 64;        // wave col quadrant
    // Chunks c0=(2q)^sw, c1=c0^1 = one aligned 32B block (R3-proven: the
    // per-lane half-swap is identical for A and B -> dot product exact).
    const int t32 = ((quad << 1) ^ (sw & 6)) * 16;

#pragma unroll 1
    for (int dt = 0; dt < 4; ++dt) {
        // stage this K-slab (8 gload_lds / thread)
#pragma unroll
        for (int i_ = 0; i_ < 4; ++i_) {
            int c_ = w * 4 + i_;        // 1KB chunk id (0..15): rows c*8..c*8+7
            int row_ = c_ * 8 + rA;
            int col_ = dt * BK + jG;
            gload_lds(z8 + (size_t)(mbase + row_) * DIM + col_,
                      As + c_ * 1024 + lane * 16);
            gload_lds(cbb + (size_t)(nbase + row_) * DIM + col_,
                      Bs + c_ * 1024 + lane * 16);
        }
        __syncthreads();   // vmcnt(0) drain; other co-resident blocks fill
#pragma unroll
        for (int h = 0; h < 2; ++h) {   // 2 B frags live at a time
            i32x8 bf0 = *(const i32x8*)(Bs + (cw + (h * 2 + 0) * 16 + l15) * BK + t32);
            i32x8 bf1 = *(const i32x8*)(Bs + (cw + (h * 2 + 1) * 16 + l15) * BK + t32);
#pragma unroll
            for (int rf = 0; rf < 4; ++rf) {
                i32x8 a = *(const i32x8*)(As + (rw + rf * 16 + l15) * BK + t32);
                acc[rf * 4 + h * 2 + 0] = __builtin_amdgcn_mfma_scale_f32_16x16x128_f8f6f4(
                    a, bf0, acc[rf * 4 + h * 2 + 0],
                    0, 0, 0, 0x7F7F7F7F, 0, 0x7F7F7F7F);
                acc[rf * 4 + h * 2 + 1] = __builtin_amdgcn_mfma_scale_f32_16x16x128_f8f6f4(
                    a, bf1, acc[rf * 4 + h * 2 + 1],
                    0, 0, 0, 0x7F7F7F7F, 0, 0x7F7F7F7F);
            }
        }
        __syncthreads();   // reads done before next stage overwrites
    }

    // epilogue: per-row argmin over this tile's 128 cols -> atomicMin.
    // C/D layout: col = lane&15, row = quad*4 + reg.
    // Packed key: monotone-uint(dist), low 13 bits = global code index.
    float es[4];
#pragma unroll
    for (int cf = 0; cf < 4; ++cf) es[cf] = Es[cw + cf * 16 + l15];

#pragma unroll
    for (int rf = 0; rf < 4; ++rf) {
#pragma unroll
        for (int r = 0; r < 4; ++r) {
            float bv = 3.4e38f; int bi = 0;
#pragma unroll
            for (int cf = 0; cf < 4; ++cf) {
                int col = cw + cf * 16 + l15;
                float dist = fmaf(-2.0f, acc[rf * 4 + cf][r], es[cf]);
                if (dist < bv) { bv = dist; bi = col; }  // strict <: low col on tie
            }
            unsigned u = __builtin_bit_cast(unsigned, bv);
            u ^= ((unsigned)(((int)u) >> 31)) | 0x80000000u;
            unsigned key = (u & 0xFFFFE000u) | (unsigned)(nbase + bi);
#pragma unroll
            for (int m = 1; m < 16; m <<= 1) {
                unsigned o = __shfl_xor(key, m, 64);
                key = o < key ? o : key;
            }
            if (l15 == 0)
                atomicMin(&candMin[mbase + rw + rf * 16 + quad * 4 + r], key);
        }
    }
}

// ---- kernel 3: gather + ST output + loss atomic ------------------------
// Pure streaming: per row one uniform key read, then 128 float4 slots.
// One plain atomicAdd per block for the loss.
__global__ __launch_bounds__(256) void gather_out(
    const float* __restrict__ z, const float* __restrict__ cb,
    const unsigned int* __restrict__ candMin, float* __restrict__ out)
{
    __shared__ float red[4];
    const int tid = threadIdx.x;
    const int w = tid >> 6, lane = tid & 63;
    float lsum = 0.f;
#pragma unroll
    for (int it = 0; it < M_ROWS / (GB_BLOCKS * 4); ++it) {
        int row = (it * GB_BLOCKS + blockIdx.x) * 4 + w;
        int k = (int)(candMin[row] & 8191u);    // uniform per wave
#pragma unroll
        for (int j = 0; j < 2; ++j) {
            int slot = lane + j * 64;
            float4 zv = ((const float4*)(z + (size_t)row * DIM))[slot];
            float4 cv = ((const float4*)(cb + (size_t)k * DIM))[slot];
            float dx = cv.x - zv.x, dy = cv.y - zv.y;
            float dz2 = cv.z - zv.z, dw = cv.w - zv.w;
            float4 o = {zv.x + dx, zv.y + dy, zv.z + dz2, zv.w + dw};  // z + sg(zq-z)
            ((float4*)(out + (size_t)row * DIM))[slot] = o;
            lsum += dx * dx + dy * dy + dz2 * dz2 + dw * dw;
        }
    }
    for (int m = 32; m; m >>= 1) lsum += __shfl_down(lsum, m, 64);
    if (lane == 0) red[w] = lsum;
    __syncthreads();
    if (tid == 0) {
        float t = (red[0] + red[1]) + (red[2] + red[3]);
        atomicAdd(out + OUT0_SIZE, t * (1.1f / (float)OUT0_SIZE));  // vq_loss = 1.1*mean
    }
}

extern "C" void kernel_launch(void* const* d_in, const int* in_sizes, int n_in,
                              void* d_out, int out_size, void* d_ws, size_t ws_size,
                              hipStream_t stream) {
    const float* z = (const float*)d_in[0];     // 16*1024*512
    const float* cb = (const float*)d_in[1];    // 8192*512
    float* out = (float*)d_out;                 // 8388608 + 1
    char* ws = (char*)d_ws;

    // ws layout (bytes)
    unsigned char* z8     = (unsigned char*)(ws);             //  8,388,608
    unsigned char* cb8    = (unsigned char*)(ws + 8388608);   //  4,194,304
    float* enorm          = (float*)(ws + 12582912);          //     32,768
    unsigned int* candMin = (unsigned int*)(ws + 12615680);   //     65,536

    convert_all<<<K_CODES / 4 + M_ROWS * DIM / 2048, 256, 0, stream>>>(
        z, cb, z8, cb8, enorm, candMin, out + OUT0_SIZE);
    gemm_argmin<<<NT * (M_ROWS / BM), 256, 0, stream>>>(z8, cb8, enorm, candMin);
    gather_out<<<GB_BLOCKS, 256, 0, stream>>>(z, cb, candMin, out);
}

// Round 16
// 223.852 us; speedup vs baseline: 1.1680x; 1.1680x over previous
//
#include <hip/hip_runtime.h>

// VQ-VAE quantization: z [16384 x 512] f32, codebook [8192 x 512] f32.
// out = concat(z_st [16384*512] f32, vq_loss [1] f32).
//
// R4: MX-fp8 (e4m3, K=128 scaled MFMA) GEMM; packed (dist|idx) u32 argmin.
// R17 (249.3 best): atomicMin candidate reduce, pure streaming gather.
// R18: single-buffer 33KB LDS for 4 blocks/CU — but (256,4) capped VGPR
// at 64 (hipcc rule measured across rounds: 2nd arg n -> cap ~256/n),
// reintroducing spill (WRITE 160MB). Occupancy DID double to 40%.
// R19 (this): same kernel, __launch_bounds__(256,2) -> cap 128 (fits the
// ~88-reg liveness, R10-measured). Occupancy now LDS-limited: 33KB ->
// 4 blocks/CU, 16 waves/CU = the clean occupancy test without spill.

#define M_ROWS 16384
#define K_CODES 8192
#define DIM 512
#define BM 128
#define BN 128
#define BK 128                 // fp8 bytes per K-step (one 16x16x128 MFMA)
#define NT (K_CODES / BN)      // 64 ktiles
#define OUT0_SIZE (M_ROWS * DIM)
#define GB_BLOCKS 1024

typedef int   i32x8 __attribute__((ext_vector_type(8)));
typedef float f32x4 __attribute__((ext_vector_type(4)));

template <bool HI>
__device__ __forceinline__ int pk8(float a, float b, int old) {
    return __builtin_amdgcn_cvt_pk_fp8_f32(a, b, old, HI);
}

__device__ __forceinline__ void gload_lds(const unsigned char* g, unsigned char* l) {
    __builtin_amdgcn_global_load_lds((const __attribute__((address_space(1))) void*)g,
                                     (__attribute__((address_space(3))) void*)l, 16, 0, 0);
}

// ---- kernel 1: fused converts + candMin init ---------------------------
__global__ __launch_bounds__(256) void convert_all(
    const float* __restrict__ z, const float* __restrict__ cb,
    unsigned char* __restrict__ z8, unsigned char* __restrict__ cb8,
    float* __restrict__ enorm, unsigned int* __restrict__ candMin,
    float* __restrict__ lossSlot)
{
    const int tid = threadIdx.x;
    if (blockIdx.x == 0 && tid == 0) *lossSlot = 0.f;   // gather accumulates
    {   // blocks 0..63 init candMin[16384]
        int gi = blockIdx.x * 256 + tid;
        if (gi < M_ROWS) candMin[gi] = 0xFFFFFFFFu;
    }
    if (blockIdx.x < K_CODES / 4) {
        const int w = tid >> 6, lane = tid & 63;
        const int row = blockIdx.x * 4 + w;
        const float* src = cb + (size_t)row * DIM + lane * 8;
        float4 a = *(const float4*)(src);
        float4 b = *(const float4*)(src + 4);
        float ns = a.x * a.x + a.y * a.y + a.z * a.z + a.w * a.w
                 + b.x * b.x + b.y * b.y + b.z * b.z + b.w * b.w;
        const float S = 8192.0f;                 // exact power of 2
        int lo = 0, hi = 0;
        lo = pk8<false>(a.x * S, a.y * S, lo); lo = pk8<true>(a.z * S, a.w * S, lo);
        hi = pk8<false>(b.x * S, b.y * S, hi); hi = pk8<true>(b.z * S, b.w * S, hi);
        *(int2*)(cb8 + (size_t)row * DIM + lane * 8) = make_int2(lo, hi);
        for (int m = 32; m; m >>= 1) ns += __shfl_down(ns, m, 64);
        if (lane == 0) enorm[row] = S * ns;      // 8192 * ||e||^2 (f32-exact norm)
    } else {
        size_t i = ((size_t)(blockIdx.x - K_CODES / 4) * 256 + tid) * 8;
        float4 a = *(const float4*)(z + i);
        float4 b = *(const float4*)(z + i + 4);
        int lo = 0, hi = 0;
        lo = pk8<false>(a.x, a.y, lo); lo = pk8<true>(a.z, a.w, lo);
        hi = pk8<false>(b.x, b.y, hi); hi = pk8<true>(b.z, b.w, hi);
        *(int2*)(z8 + i) = make_int2(lo, hi);
    }
}

// ---- kernel 2: MX-fp8 GEMM (128x128, 4 waves, 4 blocks/CU) + atomicMin -
__global__ __launch_bounds__(256, 2) void gemm_argmin(
    const unsigned char* __restrict__ z8, const unsigned char* __restrict__ cbb,
    const float* __restrict__ enorm, unsigned int* __restrict__ candMin)
{
    __shared__ alignas(32) unsigned char As[BM * BK];   // 16 KB single buffer
    __shared__ alignas(32) unsigned char Bs[BN * BK];   // 16 KB single buffer
    __shared__ float Es[BN];

    const int tid = threadIdx.x;
    const int lane = tid & 63;
    const int w = tid >> 6;             // 0..3
    // XCD remap: b&7 = XCD; XCD owns mtiles [xcd*16,xcd*16+16) (1MB A
    // slice, L2-hot); ktile advances every 128 blocks.
    const int b = blockIdx.x;
    const int xcd = b & 7;
    const int idx = b >> 3;             // 0..1023
    const int ktile = idx >> 4;         // 0..63
    const int mtile = xcd * 16 + (idx & 15);
    const int mbase = mtile * BM;
    const int nbase = ktile * BN;

    if (tid < BN) Es[tid] = enorm[nbase + tid];

    f32x4 acc[16];
#pragma unroll
    for (int i = 0; i < 16; ++i) acc[i] = (f32x4){0.f, 0.f, 0.f, 0.f};

    const int rA = lane >> 3;           // row within 8-row chunk
    const int jG = ((lane & 7) ^ rA) * 16;  // pre-swizzled global 16B chunk
    const int quad = lane >> 4;
    const int l15 = lane & 15;
    const int sw = l15 & 7;
    const int rw = (w >> 1) * 64;       // wave row quadrant
    const int cw = (w & 1) * 64;        // wave col quadrant
    // Chunks c0=(2q)^sw, c1=c0^1 = one aligned 32B block (R3-proven: the
    // per-lane half-swap is identical for A and B -> dot product exact).
    const int t32 = ((quad << 1) ^ (sw & 6)) * 16;

#pragma unroll 1
    for (int dt = 0; dt < 4; ++dt) {
        // stage this K-slab (8 gload_lds / thread)
#pragma unroll
        for (int i_ = 0; i_ < 4; ++i_) {
            int c_ = w * 4 + i_;        // 1KB chunk id (0..15): rows c*8..c*8+7
            int row_ = c_ * 8 + rA;
            int col_ = dt * BK + jG;
            gload_lds(z8 + (size_t)(mbase + row_) * DIM + col_,
                      As + c_ * 1024 + lane * 16);
            gload_lds(cbb + (size_t)(nbase + row_) * DIM + col_,
                      Bs + c_ * 1024 + lane * 16);
        }
        __syncthreads();   // vmcnt(0) drain; other co-resident blocks fill
#pragma unroll
        for (int h = 0; h < 2; ++h) {   // 2 B frags live at a time
            i32x8 bf0 = *(const i32x8*)(Bs + (cw + (h * 2 + 0) * 16 + l15) * BK + t32);
            i32x8 bf1 = *(const i32x8*)(Bs + (cw + (h * 2 + 1) * 16 + l15) * BK + t32);
#pragma unroll
            for (int rf = 0; rf < 4; ++rf) {
                i32x8 a = *(const i32x8*)(As + (rw + rf * 16 + l15) * BK + t32);
                acc[rf * 4 + h * 2 + 0] = __builtin_amdgcn_mfma_scale_f32_16x16x128_f8f6f4(
                    a, bf0, acc[rf * 4 + h * 2 + 0],
                    0, 0, 0, 0x7F7F7F7F, 0, 0x7F7F7F7F);
                acc[rf * 4 + h * 2 + 1] = __builtin_amdgcn_mfma_scale_f32_16x16x128_f8f6f4(
                    a, bf1, acc[rf * 4 + h * 2 + 1],
                    0, 0, 0, 0x7F7F7F7F, 0, 0x7F7F7F7F);
            }
        }
        __syncthreads();   // reads done before next stage overwrites
    }

    // epilogue: per-row argmin over this tile's 128 cols -> atomicMin.
    // C/D layout: col = lane&15, row = quad*4 + reg.
    // Packed key: monotone-uint(dist), low 13 bits = global code index.
    float es[4];
#pragma unroll
    for (int cf = 0; cf < 4; ++cf) es[cf] = Es[cw + cf * 16 + l15];

#pragma unroll
    for (int rf = 0; rf < 4; ++rf) {
#pragma unroll
        for (int r = 0; r < 4; ++r) {
            float bv = 3.4e38f; int bi = 0;
#pragma unroll
            for (int cf = 0; cf < 4; ++cf) {
                int col = cw + cf * 16 + l15;
                float dist = fmaf(-2.0f, acc[rf * 4 + cf][r], es[cf]);
                if (dist < bv) { bv = dist; bi = col; }  // strict <: low col on tie
            }
            unsigned u = __builtin_bit_cast(unsigned, bv);
            u ^= ((unsigned)(((int)u) >> 31)) | 0x80000000u;
            unsigned key = (u & 0xFFFFE000u) | (unsigned)(nbase + bi);
#pragma unroll
            for (int m = 1; m < 16; m <<= 1) {
                unsigned o = __shfl_xor(key, m, 64);
                key = o < key ? o : key;
            }
            if (l15 == 0)
                atomicMin(&candMin[mbase + rw + rf * 16 + quad * 4 + r], key);
        }
    }
}

// ---- kernel 3: gather + ST output + loss atomic ------------------------
// Pure streaming: per row one uniform key read, then 128 float4 slots.
// One plain atomicAdd per block for the loss.
__global__ __launch_bounds__(256) void gather_out(
    const float* __restrict__ z, const float* __restrict__ cb,
    const unsigned int* __restrict__ candMin, float* __restrict__ out)
{
    __shared__ float red[4];
    const int tid = threadIdx.x;
    const int w = tid >> 6, lane = tid & 63;
    float lsum = 0.f;
#pragma unroll
    for (int it = 0; it < M_ROWS / (GB_BLOCKS * 4); ++it) {
        int row = (it * GB_BLOCKS + blockIdx.x) * 4 + w;
        int k = (int)(candMin[row] & 8191u);    // uniform per wave
#pragma unroll
        for (int j = 0; j < 2; ++j) {
            int slot = lane + j * 64;
            float4 zv = ((const float4*)(z + (size_t)row * DIM))[slot];
            float4 cv = ((const float4*)(cb + (size_t)k * DIM))[slot];
            float dx = cv.x - zv.x, dy = cv.y - zv.y;
            float dz2 = cv.z - zv.z, dw = cv.w - zv.w;
            float4 o = {zv.x + dx, zv.y + dy, zv.z + dz2, zv.w + dw};  // z + sg(zq-z)
            ((float4*)(out + (size_t)row * DIM))[slot] = o;
            lsum += dx * dx + dy * dy + dz2 * dz2 + dw * dw;
        }
    }
    for (int m = 32; m; m >>= 1) lsum += __shfl_down(lsum, m, 64);
    if (lane == 0) red[w] = lsum;
    __syncthreads();
    if (tid == 0) {
        float t = (red[0] + red[1]) + (red[2] + red[3]);
        atomicAdd(out + OUT0_SIZE, t * (1.1f / (float)OUT0_SIZE));  // vq_loss = 1.1*mean
    }
}

extern "C" void kernel_launch(void* const* d_in, const int* in_sizes, int n_in,
                              void* d_out, int out_size, void* d_ws, size_t ws_size,
                              hipStream_t stream) {
    const float* z = (const float*)d_in[0];     // 16*1024*512
    const float* cb = (const float*)d_in[1];    // 8192*512
    float* out = (float*)d_out;                 // 8388608 + 1
    char* ws = (char*)d_ws;

    // ws layout (bytes)
    unsigned char* z8     = (unsigned char*)(ws);             //  8,388,608
    unsigned char* cb8    = (unsigned char*)(ws + 8388608);   //  4,194,304
    float* enorm          = (float*)(ws + 12582912);          //     32,768
    unsigned int* candMin = (unsigned int*)(ws + 12615680);   //     65,536

    convert_all<<<K_CODES / 4 + M_ROWS * DIM / 2048, 256, 0, stream>>>(
        z, cb, z8, cb8, enorm, candMin, out + OUT0_SIZE);
    gemm_argmin<<<NT * (M_ROWS / BM), 256, 0, stream>>>(z8, cb8, enorm, candMin);
    gather_out<<<GB_BLOCKS, 256, 0, stream>>>(z, cb, candMin, out);
}

// Round 17
// 221.783 us; speedup vs baseline: 1.1789x; 1.0093x over previous
//
#include <hip/hip_runtime.h>

// VQ-VAE quantization: z [16384 x 512] f32, codebook [8192 x 512] f32.
// out = concat(z_st [16384*512] f32, vq_loss [1] f32).
//
// R4: MX-fp8 (e4m3, K=128 scaled MFMA) GEMM; packed (dist|idx) u32 argmin.
// R17: atomicMin candidate reduce, pure streaming gather.
// R19 (123.2µs gemm, 223.9 total best): single-buffer 33KB LDS + (256,2)
// -> 4 blocks/CU, no spill. Occupancy 21.7->29.6% bought 25µs: the
// single-buffer + cross-block-overlap structure beats every explicit
// pipeline tried (R11/R12/R14 all null or worse).
// R20 (this): Es LDS buffer -> registers. LDS was 33280B (As 16K + Bs 16K
// + Es 512B) = 4.8 blocks/CU -> 4. Each thread only needs 4 enorm values
// (epilogue); load them to regs at start (64B-coalesced per quad, L2-hot).
// LDS = 32768 exactly -> 5 blocks/CU (163840 = 160KB exact). +25%
// co-resident work, same proven structure, everything else identical.

#define M_ROWS 16384
#define K_CODES 8192
#define DIM 512
#define BM 128
#define BN 128
#define BK 128                 // fp8 bytes per K-step (one 16x16x128 MFMA)
#define NT (K_CODES / BN)      // 64 ktiles
#define OUT0_SIZE (M_ROWS * DIM)
#define GB_BLOCKS 1024

typedef int   i32x8 __attribute__((ext_vector_type(8)));
typedef float f32x4 __attribute__((ext_vector_type(4)));

template <bool HI>
__device__ __forceinline__ int pk8(float a, float b, int old) {
    return __builtin_amdgcn_cvt_pk_fp8_f32(a, b, old, HI);
}

__device__ __forceinline__ void gload_lds(const unsigned char* g, unsigned char* l) {
    __builtin_amdgcn_global_load_lds((const __attribute__((address_space(1))) void*)g,
                                     (__attribute__((address_space(3))) void*)l, 16, 0, 0);
}

// ---- kernel 1: fused converts + candMin init ---------------------------
__global__ __launch_bounds__(256) void convert_all(
    const float* __restrict__ z, const float* __restrict__ cb,
    unsigned char* __restrict__ z8, unsigned char* __restrict__ cb8,
    float* __restrict__ enorm, unsigned int* __restrict__ candMin,
    float* __restrict__ lossSlot)
{
    const int tid = threadIdx.x;
    if (blockIdx.x == 0 && tid == 0) *lossSlot = 0.f;   // gather accumulates
    {   // blocks 0..63 init candMin[16384]
        int gi = blockIdx.x * 256 + tid;
        if (gi < M_ROWS) candMin[gi] = 0xFFFFFFFFu;
    }
    if (blockIdx.x < K_CODES / 4) {
        const int w = tid >> 6, lane = tid & 63;
        const int row = blockIdx.x * 4 + w;
        const float* src = cb + (size_t)row * DIM + lane * 8;
        float4 a = *(const float4*)(src);
        float4 b = *(const float4*)(src + 4);
        float ns = a.x * a.x + a.y * a.y + a.z * a.z + a.w * a.w
                 + b.x * b.x + b.y * b.y + b.z * b.z + b.w * b.w;
        const float S = 8192.0f;                 // exact power of 2
        int lo = 0, hi = 0;
        lo = pk8<false>(a.x * S, a.y * S, lo); lo = pk8<true>(a.z * S, a.w * S, lo);
        hi = pk8<false>(b.x * S, b.y * S, hi); hi = pk8<true>(b.z * S, b.w * S, hi);
        *(int2*)(cb8 + (size_t)row * DIM + lane * 8) = make_int2(lo, hi);
        for (int m = 32; m; m >>= 1) ns += __shfl_down(ns, m, 64);
        if (lane == 0) enorm[row] = S * ns;      // 8192 * ||e||^2 (f32-exact norm)
    } else {
        size_t i = ((size_t)(blockIdx.x - K_CODES / 4) * 256 + tid) * 8;
        float4 a = *(const float4*)(z + i);
        float4 b = *(const float4*)(z + i + 4);
        int lo = 0, hi = 0;
        lo = pk8<false>(a.x, a.y, lo); lo = pk8<true>(a.z, a.w, lo);
        hi = pk8<false>(b.x, b.y, hi); hi = pk8<true>(b.z, b.w, hi);
        *(int2*)(z8 + i) = make_int2(lo, hi);
    }
}

// ---- kernel 2: MX-fp8 GEMM (128x128, 4 waves, 5 blocks/CU) + atomicMin -
__global__ __launch_bounds__(256, 2) void gemm_argmin(
    const unsigned char* __restrict__ z8, const unsigned char* __restrict__ cbb,
    const float* __restrict__ enorm, unsigned int* __restrict__ candMin)
{
    __shared__ alignas(32) unsigned char As[BM * BK];   // 16 KB single buffer
    __shared__ alignas(32) unsigned char Bs[BN * BK];   // 16 KB single buffer
    // no Es: LDS = 32768 B exactly -> 5 blocks/CU

    const int tid = threadIdx.x;
    const int lane = tid & 63;
    const int w = tid >> 6;             // 0..3
    // XCD remap: b&7 = XCD; XCD owns mtiles [xcd*16,xcd*16+16) (1MB A
    // slice, L2-hot); ktile advances every 128 blocks.
    const int b = blockIdx.x;
    const int xcd = b & 7;
    const int idx = b >> 3;             // 0..1023
    const int ktile = idx >> 4;         // 0..63
    const int mtile = xcd * 16 + (idx & 15);
    const int mbase = mtile * BM;
    const int nbase = ktile * BN;

    const int rA = lane >> 3;           // row within 8-row chunk
    const int jG = ((lane & 7) ^ rA) * 16;  // pre-swizzled global 16B chunk
    const int quad = lane >> 4;
    const int l15 = lane & 15;
    const int sw = l15 & 7;
    const int rw = (w >> 1) * 64;       // wave row quadrant
    const int cw = (w & 1) * 64;        // wave col quadrant
    // Chunks c0=(2q)^sw, c1=c0^1 = one aligned 32B block (R3-proven: the
    // per-lane half-swap is identical for A and B -> dot product exact).
    const int t32 = ((quad << 1) ^ (sw & 6)) * 16;

    // epilogue norms straight to regs (64B-coalesced per quad, L2-hot)
    float es[4];
#pragma unroll
    for (int cf = 0; cf < 4; ++cf) es[cf] = enorm[nbase + cw + cf * 16 + l15];

    f32x4 acc[16];
#pragma unroll
    for (int i = 0; i < 16; ++i) acc[i] = (f32x4){0.f, 0.f, 0.f, 0.f};

#pragma unroll 1
    for (int dt = 0; dt < 4; ++dt) {
        // stage this K-slab (8 gload_lds / thread)
#pragma unroll
        for (int i_ = 0; i_ < 4; ++i_) {
            int c_ = w * 4 + i_;        // 1KB chunk id (0..15): rows c*8..c*8+7
            int row_ = c_ * 8 + rA;
            int col_ = dt * BK + jG;
            gload_lds(z8 + (size_t)(mbase + row_) * DIM + col_,
                      As + c_ * 1024 + lane * 16);
            gload_lds(cbb + (size_t)(nbase + row_) * DIM + col_,
                      Bs + c_ * 1024 + lane * 16);
        }
        __syncthreads();   // vmcnt(0) drain; other co-resident blocks fill
#pragma unroll
        for (int h = 0; h < 2; ++h) {   // 2 B frags live at a time
            i32x8 bf0 = *(const i32x8*)(Bs + (cw + (h * 2 + 0) * 16 + l15) * BK + t32);
            i32x8 bf1 = *(const i32x8*)(Bs + (cw + (h * 2 + 1) * 16 + l15) * BK + t32);
#pragma unroll
            for (int rf = 0; rf < 4; ++rf) {
                i32x8 a = *(const i32x8*)(As + (rw + rf * 16 + l15) * BK + t32);
                acc[rf * 4 + h * 2 + 0] = __builtin_amdgcn_mfma_scale_f32_16x16x128_f8f6f4(
                    a, bf0, acc[rf * 4 + h * 2 + 0],
                    0, 0, 0, 0x7F7F7F7F, 0, 0x7F7F7F7F);
                acc[rf * 4 + h * 2 + 1] = __builtin_amdgcn_mfma_scale_f32_16x16x128_f8f6f4(
                    a, bf1, acc[rf * 4 + h * 2 + 1],
                    0, 0, 0, 0x7F7F7F7F, 0, 0x7F7F7F7F);
            }
        }
        __syncthreads();   // reads done before next stage overwrites
    }

    // epilogue: per-row argmin over this tile's 128 cols -> atomicMin.
    // C/D layout: col = lane&15, row = quad*4 + reg.
    // Packed key: monotone-uint(dist), low 13 bits = global code index.
#pragma unroll
    for (int rf = 0; rf < 4; ++rf) {
#pragma unroll
        for (int r = 0; r < 4; ++r) {
            float bv = 3.4e38f; int bi = 0;
#pragma unroll
            for (int cf = 0; cf < 4; ++cf) {
                int col = cw + cf * 16 + l15;
                float dist = fmaf(-2.0f, acc[rf * 4 + cf][r], es[cf]);
                if (dist < bv) { bv = dist; bi = col; }  // strict <: low col on tie
            }
            unsigned u = __builtin_bit_cast(unsigned, bv);
            u ^= ((unsigned)(((int)u) >> 31)) | 0x80000000u;
            unsigned key = (u & 0xFFFFE000u) | (unsigned)(nbase + bi);
#pragma unroll
            for (int m = 1; m < 16; m <<= 1) {
                unsigned o = __shfl_xor(key, m, 64);
                key = o < key ? o : key;
            }
            if (l15 == 0)
                atomicMin(&candMin[mbase + rw + rf * 16 + quad * 4 + r], key);
        }
    }
}

// ---- kernel 3: gather + ST output + loss atomic ------------------------
// Pure streaming: per row one uniform key read, then 128 float4 slots.
// One plain atomicAdd per block for the loss.
__global__ __launch_bounds__(256) void gather_out(
    const float* __restrict__ z, const float* __restrict__ cb,
    const unsigned int* __restrict__ candMin, float* __restrict__ out)
{
    __shared__ float red[4];
    const int tid = threadIdx.x;
    const int w = tid >> 6, lane = tid & 63;
    float lsum = 0.f;
#pragma unroll
    for (int it = 0; it < M_ROWS / (GB_BLOCKS * 4); ++it) {
        int row = (it * GB_BLOCKS + blockIdx.x) * 4 + w;
        int k = (int)(candMin[row] & 8191u);    // uniform per wave
#pragma unroll
        for (int j = 0; j < 2; ++j) {
            int slot = lane + j * 64;
            float4 zv = ((const float4*)(z + (size_t)row * DIM))[slot];
            float4 cv = ((const float4*)(cb + (size_t)k * DIM))[slot];
            float dx = cv.x - zv.x, dy = cv.y - zv.y;
            float dz2 = cv.z - zv.z, dw = cv.w - zv.w;
            float4 o = {zv.x + dx, zv.y + dy, zv.z + dz2, zv.w + dw};  // z + sg(zq-z)
            ((float4*)(out + (size_t)row * DIM))[slot] = o;
            lsum += dx * dx + dy * dy + dz2 * dz2 + dw * dw;
        }
    }
    for (int m = 32; m; m >>= 1) lsum += __shfl_down(lsum, m, 64);
    if (lane == 0) red[w] = lsum;
    __syncthreads();
    if (tid == 0) {
        float t = (red[0] + red[1]) + (red[2] + red[3]);
        atomicAdd(out + OUT0_SIZE, t * (1.1f / (float)OUT0_SIZE));  // vq_loss = 1.1*mean
    }
}

extern "C" void kernel_launch(void* const* d_in, const int* in_sizes, int n_in,
                              void* d_out, int out_size, void* d_ws, size_t ws_size,
                              hipStream_t stream) {
    const float* z = (const float*)d_in[0];     // 16*1024*512
    const float* cb = (const float*)d_in[1];    // 8192*512
    float* out = (float*)d_out;                 // 8388608 + 1
    char* ws = (char*)d_ws;

    // ws layout (bytes)
    unsigned char* z8     = (unsigned char*)(ws);             //  8,388,608
    unsigned char* cb8    = (unsigned char*)(ws + 8388608);   //  4,194,304
    float* enorm          = (float*)(ws + 12582912);          //     32,768
    unsigned int* candMin = (unsigned int*)(ws + 12615680);   //     65,536

    convert_all<<<K_CODES / 4 + M_ROWS * DIM / 2048, 256, 0, stream>>>(
        z, cb, z8, cb8, enorm, candMin, out + OUT0_SIZE);
    gemm_argmin<<<NT * (M_ROWS / BM), 256, 0, stream>>>(z8, cb8, enorm, candMin);
    gather_out<<<GB_BLOCKS, 256, 0, stream>>>(z, cb, candMin, out);
}